// Round 2
// baseline (11026.231 us; speedup 1.0000x reference)
//
#include <hip/hip_runtime.h>
#include <stdint.h>

#define T_DIM 512
#define B_DIM 256
#define OBS_DIM 128
#define H_DIM 256
#define A_DIM 32
#define TB (T_DIM*B_DIM)   // 131072

typedef unsigned short u16;
typedef unsigned int   u32;

__device__ __forceinline__ float bf2f(u16 v){ return __uint_as_float(((u32)v)<<16); }
__device__ __forceinline__ u16 f2bf(float f){
    u32 x = __float_as_uint(f);
    u32 r = x + 0x7fffu + ((x>>16)&1u);   // round-to-nearest-even
    return (u16)(r>>16);
}
__device__ __forceinline__ float2 bfpair(u32 u){
    return make_float2(__uint_as_float(u<<16), __uint_as_float(u & 0xffff0000u));
}

// ---------------------------------------------------------------------------
// dones dtype probe (u8 bool vs i32 vs f32) via nonzero byte positions mod 4.
// bit0: nonzero @ pos%4==1 (only u8). bit1: nonzero @ pos%4>=2 (f32 1.0f).
// ---------------------------------------------------------------------------
__global__ void zero_flags_kernel(int* p){ if(threadIdx.x<4) p[threadIdx.x]=0; }

__global__ void detect_kernel(const unsigned char* __restrict__ d, int n, int* __restrict__ flags){
    int f=0;
    for(int p = blockIdx.x*blockDim.x+threadIdx.x; p<n; p += gridDim.x*blockDim.x){
        if(d[p]){ int m=p&3; if(m==1) f|=1; else if(m>=2) f|=2; }
    }
    if(f) atomicOr(flags, f);
}

// Whr|Whz|Whn (f32 [256][256] each) -> bf16 [3][256][256]
__global__ void cvt_wh_kernel(const float* __restrict__ Whr, const float* __restrict__ Whz,
                              const float* __restrict__ Whn, u16* __restrict__ dst){
    int i = blockIdx.x*blockDim.x + threadIdx.x;
    if(i < 65536){
        dst[i]          = f2bf(Whr[i]);
        dst[65536 + i]  = f2bf(Whz[i]);
        dst[131072 + i] = f2bf(Whn[i]);
    }
}

// ---------------------------------------------------------------------------
// Generic f32-accumulate GEMM: C[M,N](bf16) = opt_relu(A[M,K] @ W[K,N] + bias)
// A f32 (ABF16=0) or bf16 (ABF16=1). 128x128 tile, BK=16, 256 thr, 8x8/thread.
// M%128==0, N%128==0, K%16==0 at every call site.
// ---------------------------------------------------------------------------
template<int RELU, int ABF16>
__global__ __launch_bounds__(256)
void gemm_kernel(const void* __restrict__ A_, const float* __restrict__ W,
                 const float* __restrict__ bias, u16* __restrict__ C,
                 int M, int N, int K)
{
    __shared__ float As[16][128];   // As[k][m]
    __shared__ float Ws[16][128];   // Ws[k][n]
    const int tid = threadIdx.x;
    const int tr = tid>>4, tc = tid&15;
    const int lar = tid>>1, lac = (tid&1)*8;
    const int lwr = tid>>4, lwc = (tid&15)*8;
    const int rowBase = blockIdx.y*128;
    const int colBase = blockIdx.x*128;

    float acc[8][8];
    #pragma unroll
    for(int i=0;i<8;i++){
        #pragma unroll
        for(int j=0;j<8;j++) acc[i][j]=0.f;
    }

    for(int kb=0; kb<K; kb+=16){
        if(ABF16){
            const u16* Ab = (const u16*)A_;
            uint4 u = *(const uint4*)(Ab + (size_t)(rowBase+lar)*K + kb + lac);
            const u16* us = (const u16*)&u;
            #pragma unroll
            for(int i=0;i<8;i++) As[lac+i][lar] = bf2f(us[i]);
        } else {
            const float* Af = (const float*)A_;
            const float4* p = (const float4*)(Af + (size_t)(rowBase+lar)*K + kb + lac);
            float4 a0=p[0], a1=p[1];
            As[lac+0][lar]=a0.x; As[lac+1][lar]=a0.y; As[lac+2][lar]=a0.z; As[lac+3][lar]=a0.w;
            As[lac+4][lar]=a1.x; As[lac+5][lar]=a1.y; As[lac+6][lar]=a1.z; As[lac+7][lar]=a1.w;
        }
        {
            const float4* p = (const float4*)(W + (size_t)(kb+lwr)*N + colBase + lwc);
            float4 w0 = p[0], w1 = p[1];
            *(float4*)&Ws[lwr][lwc]   = w0;
            *(float4*)&Ws[lwr][lwc+4] = w1;
        }
        __syncthreads();
        #pragma unroll
        for(int kk=0;kk<16;kk++){
            float4 a0 = *(const float4*)&As[kk][tr*8];
            float4 a1 = *(const float4*)&As[kk][tr*8+4];
            float4 w0 = *(const float4*)&Ws[kk][tc*8];
            float4 w1 = *(const float4*)&Ws[kk][tc*8+4];
            float av[8]={a0.x,a0.y,a0.z,a0.w,a1.x,a1.y,a1.z,a1.w};
            float wv[8]={w0.x,w0.y,w0.z,w0.w,w1.x,w1.y,w1.z,w1.w};
            #pragma unroll
            for(int i=0;i<8;i++){
                #pragma unroll
                for(int j=0;j<8;j++) acc[i][j] = fmaf(av[i], wv[j], acc[i][j]);
            }
        }
        __syncthreads();
    }

    float bv[8];
    #pragma unroll
    for(int j=0;j<8;j++) bv[j] = bias[colBase + tc*8 + j];
    #pragma unroll
    for(int i=0;i<8;i++){
        u16 h[8];
        #pragma unroll
        for(int j=0;j<8;j++){
            float v = acc[i][j] + bv[j];
            if(RELU) v = fmaxf(v, 0.f);
            h[j] = f2bf(v);
        }
        *(uint4*)(C + (size_t)(rowBase + tr*8 + i)*N + colBase + tc*8) = *(uint4*)h;
    }
}

// ---------------------------------------------------------------------------
// GRU scan over one T-chunk. 64 blocks x 192 threads; block owns batch rows
// 4b..4b+3 for chunk steps t0..t0+Tc-1. h carried in ws (f32, raw/un-reset).
// gi_c / y_c are chunk-local [Tc,B,*]; dones indexed globally.
// ---------------------------------------------------------------------------
__global__ __launch_bounds__(192)
void scan_kernel(const u16* __restrict__ gi, const void* __restrict__ dones,
                 const int* __restrict__ flags, const u16* __restrict__ Wh,
                 const float* __restrict__ bhn, float* __restrict__ h_carry,
                 u16* __restrict__ y, int t0, int Tc)
{
    __shared__ float hs[4][256];        // reset-applied h for current step
    __shared__ float accb[3][4][256];   // r/z/n matvec partials
    const int tid = threadIdx.x;
    const int b0  = blockIdx.x*4;
    const int fl  = flags[0];
    const int mode = (fl&1) ? 0 : ((fl&2) ? 2 : 1);  // 0=u8, 1=i32, 2=f32
    const int mat = tid>>6;          // 0..2
    const int jg  = tid&63;
    const int j0  = jg*4;
    const u16* Wm = Wh + (size_t)mat*65536;

    auto getdone = [&](int t, int row)->bool{
        int idx = t*B_DIM + row;
        if(mode==0) return ((const unsigned char*)dones)[idx] != 0;
        if(mode==1) return ((const int*)dones)[idx] != 0;
        return ((const float*)dones)[idx] != 0.f;
    };

    // init: load carry, apply reset for this chunk's first step
    for(int idx=tid; idx<1024; idx+=192){
        int g = idx>>8, j = idx&255;
        bool d0 = getdone(t0, b0+g);
        hs[g][j] = d0 ? 0.f : h_carry[(size_t)(b0+g)*H_DIM + j];
    }
    __syncthreads();

    for(int t=0; t<Tc; ++t){
        // dot phase: acc[g][c] = sum_k hs[g][k] * Wm[k][j0+c]
        float acc[4][4];
        #pragma unroll
        for(int g=0;g<4;g++){ acc[g][0]=0.f; acc[g][1]=0.f; acc[g][2]=0.f; acc[g][3]=0.f; }
        for(int k4=0; k4<64; ++k4){
            float4 h4[4];
            #pragma unroll
            for(int g=0;g<4;g++) h4[g] = *(const float4*)&hs[g][k4*4];
            #pragma unroll
            for(int kk=0; kk<4; ++kk){
                int k = k4*4+kk;
                uint2 wv = *(const uint2*)(Wm + (size_t)k*256 + j0);
                float2 wa = bfpair(wv.x), wb = bfpair(wv.y);
                #pragma unroll
                for(int g=0; g<4; ++g){
                    float hk = (kk==0)?h4[g].x:(kk==1)?h4[g].y:(kk==2)?h4[g].z:h4[g].w;
                    acc[g][0] = fmaf(hk, wa.x, acc[g][0]);
                    acc[g][1] = fmaf(hk, wa.y, acc[g][1]);
                    acc[g][2] = fmaf(hk, wb.x, acc[g][2]);
                    acc[g][3] = fmaf(hk, wb.y, acc[g][3]);
                }
            }
        }
        #pragma unroll
        for(int g=0;g<4;g++)
            *(float4*)&accb[mat][g][j0] = make_float4(acc[g][0],acc[g][1],acc[g][2],acc[g][3]);
        __syncthreads();

        // gate phase
        for(int j=tid; j<256; j+=192){
            float bh = bhn[j];
            #pragma unroll
            for(int g=0; g<4; ++g){
                int row = b0+g;
                size_t gbase = ((size_t)t*B_DIM + row)*768;
                float ir = bf2f(gi[gbase + j]);
                float iz = bf2f(gi[gbase + 256 + j]);
                float in = bf2f(gi[gbase + 512 + j]);
                float r = 1.f/(1.f + __expf(-(ir + accb[0][g][j])));
                float z = 1.f/(1.f + __expf(-(iz + accb[1][g][j])));
                float n = tanhf(in + r*(accb[2][g][j] + bh));
                float ho = hs[g][j];
                float hn = (1.f - z)*n + z*ho;
                y[((size_t)t*B_DIM + row)*H_DIM + j] = f2bf(hn);
                if(t < Tc-1){
                    bool dn = getdone(t0+t+1, row);
                    hs[g][j] = dn ? 0.f : hn;   // pre-apply next step's reset
                } else {
                    hs[g][j] = hn;              // raw carry-out
                }
            }
        }
        __syncthreads();
    }

    for(int idx=tid; idx<1024; idx+=192){
        int g=idx>>8, j=idx&255;
        h_carry[(size_t)(b0+g)*H_DIM + j] = hs[g][j];
    }
}

// ---------------------------------------------------------------------------
// Actor head stage 2: logits[rows,32] = ah[rows,256] @ W_a2 + b_a2 - (1-avail)*1e10
// ---------------------------------------------------------------------------
__global__ __launch_bounds__(256)
void actor2_kernel(const u16* __restrict__ ah, const float* __restrict__ W_a2,
                   const float* __restrict__ b_a2, const float* __restrict__ avail,
                   float* __restrict__ logits)
{
    __shared__ u16 ahs[64][264];
    const int tid = threadIdx.x;
    const int r0 = blockIdx.x*64;
    {
        int row = tid & 63;
        int c0 = (tid >> 6) * 64;
        const uint4* gp = (const uint4*)(ah + (size_t)(r0+row)*H_DIM + c0);
        #pragma unroll
        for(int q=0;q<8;q++){
            uint4 u = gp[q];
            u32* dst = (u32*)&ahs[row][c0 + q*8];
            dst[0]=u.x; dst[1]=u.y; dst[2]=u.z; dst[3]=u.w;
        }
    }
    __syncthreads();
    const int c  = tid & 31;
    const int rg = tid >> 5;   // 0..7
    float acc[8]={0.f,0.f,0.f,0.f,0.f,0.f,0.f,0.f};
    float bc = b_a2[c];
    for(int k=0;k<H_DIM;k+=4){
        float w0 = W_a2[(k+0)*A_DIM + c];
        float w1 = W_a2[(k+1)*A_DIM + c];
        float w2 = W_a2[(k+2)*A_DIM + c];
        float w3 = W_a2[(k+3)*A_DIM + c];
        #pragma unroll
        for(int rr=0;rr<8;rr++){
            uint2 av = *(const uint2*)&ahs[rg*8+rr][k];
            float2 p0 = bfpair(av.x), p1 = bfpair(av.y);
            acc[rr] = fmaf(p0.x,w0,fmaf(p0.y,w1,fmaf(p1.x,w2,fmaf(p1.y,w3,acc[rr]))));
        }
    }
    #pragma unroll
    for(int rr=0;rr<8;rr++){
        int grow = r0 + rg*8 + rr;
        float av = avail[(size_t)grow*A_DIM + c];
        logits[(size_t)grow*A_DIM + c] = acc[rr] + bc - (1.f-av)*1e10f;
    }
}

// ---------------------------------------------------------------------------
// Critic head stage 2: value[row] = ch[row,256] @ W_c2 + b_c2. Wave per row.
// ---------------------------------------------------------------------------
__global__ __launch_bounds__(256)
void critic2_kernel(const u16* __restrict__ ch, const float* __restrict__ W_c2,
                    const float* __restrict__ b_c2, float* __restrict__ value)
{
    const int lane = threadIdx.x & 63;
    const int wid  = threadIdx.x >> 6;
    const int row  = blockIdx.x*4 + wid;
    uint2 av = *(const uint2*)(ch + (size_t)row*H_DIM + lane*4);
    float2 p0 = bfpair(av.x), p1 = bfpair(av.y);
    float4 wv = *(const float4*)(W_c2 + lane*4);
    float acc = p0.x*wv.x + p0.y*wv.y + p1.x*wv.z + p1.y*wv.w;
    #pragma unroll
    for(int off=32; off>0; off>>=1) acc += __shfl_down(acc, off, 64);
    if(lane==0) value[row] = acc + b_c2[0];
}

// ---------------------------------------------------------------------------
extern "C" void kernel_launch(void* const* d_in, const int* in_sizes, int n_in,
                              void* d_out, int out_size, void* d_ws, size_t ws_size,
                              hipStream_t stream)
{
    const float* hidden = (const float*)d_in[0];
    const float* obs    = (const float*)d_in[1];
    const void*  dones  = d_in[2];
    const float* avail  = (const float*)d_in[3];
    const float* W_emb  = (const float*)d_in[4];
    const float* b_emb  = (const float*)d_in[5];
    const float* Wi     = (const float*)d_in[6];
    const float* bi     = (const float*)d_in[7];
    const float* Whr    = (const float*)d_in[8];
    const float* Whz    = (const float*)d_in[9];
    const float* Whn    = (const float*)d_in[10];
    const float* bhn    = (const float*)d_in[11];
    const float* W_a1   = (const float*)d_in[12];
    const float* b_a1   = (const float*)d_in[13];
    const float* W_a2   = (const float*)d_in[14];
    const float* b_a2   = (const float*)d_in[15];
    const float* W_c1   = (const float*)d_in[16];
    const float* b_c1   = (const float*)d_in[17];
    const float* W_c2   = (const float*)d_in[18];
    const float* b_c2   = (const float*)d_in[19];

    float* out_hidden = (float*)d_out;                       // 65536
    float* out_logits = out_hidden + (size_t)B_DIM*H_DIM;    // 4194304
    float* out_value  = out_logits + (size_t)TB*A_DIM;       // 131072

    // ---- workspace layout, chunk size adapted to ws_size (deterministic) ----
    const size_t fixed = 393216 /*wh*/ + 262144 /*h_carry*/ + 256 /*flags*/;
    int Tc = 4;
    for(int cand = 64; cand >= 4; cand >>= 1){
        size_t need = fixed + (size_t)cand*393216 /*gi*/ + (size_t)cand*4*131072 /*emb,y,ah,ch*/;
        if(need <= ws_size){ Tc = cand; break; }
    }
    const int NC = T_DIM / Tc;

    uint8_t* ws = (uint8_t*)d_ws;
    size_t off = 0;
    u16*  wh_b    = (u16*)(ws + off); off += 393216;
    float* h_carry= (float*)(ws + off); off += 262144;
    int*  flags   = (int*)(ws + off); off += 256;
    u16*  gi_c    = (u16*)(ws + off); off += (size_t)Tc*393216;
    u16*  emb_c   = (u16*)(ws + off); off += (size_t)Tc*131072;
    u16*  y_c     = (u16*)(ws + off); off += (size_t)Tc*131072;
    u16*  ah_c    = (u16*)(ws + off); off += (size_t)Tc*131072;
    u16*  ch_c    = (u16*)(ws + off); off += (size_t)Tc*131072;

    zero_flags_kernel<<<1, 64, 0, stream>>>(flags);
    detect_kernel<<<64, 256, 0, stream>>>((const unsigned char*)dones, TB, flags);
    cvt_wh_kernel<<<256, 256, 0, stream>>>(Whr, Whz, Whn, wh_b);
    hipMemcpyAsync(h_carry, hidden, (size_t)B_DIM*H_DIM*sizeof(float),
                   hipMemcpyDeviceToDevice, stream);

    const int Mc = Tc*B_DIM;          // rows per chunk
    const int gy = Mc/128;            // gemm grid.y

    for(int c = 0; c < NC; ++c){
        const int t0 = c*Tc;
        const float* obs_c = obs + (size_t)t0*B_DIM*OBS_DIM;
        // emb = relu(obs @ W_emb + b_emb)
        gemm_kernel<1,0><<<dim3(2,gy), 256, 0, stream>>>(obs_c, W_emb, b_emb, emb_c, Mc, 256, 128);
        // gi = emb @ Wi + bi
        gemm_kernel<0,1><<<dim3(6,gy), 256, 0, stream>>>(emb_c, Wi, bi, gi_c, Mc, 768, 256);
        // GRU scan chunk
        scan_kernel<<<64, 192, 0, stream>>>(gi_c, dones, flags, wh_b, bhn, h_carry, y_c, t0, Tc);
        // actor head
        gemm_kernel<1,1><<<dim3(2,gy), 256, 0, stream>>>(y_c, W_a1, b_a1, ah_c, Mc, 256, 256);
        actor2_kernel<<<Mc/64, 256, 0, stream>>>(ah_c, W_a2, b_a2,
                                                 avail + (size_t)t0*B_DIM*A_DIM,
                                                 out_logits + (size_t)t0*B_DIM*A_DIM);
        // critic head
        gemm_kernel<1,1><<<dim3(2,gy), 256, 0, stream>>>(y_c, W_c1, b_c1, ch_c, Mc, 256, 256);
        critic2_kernel<<<Mc/4, 256, 0, stream>>>(ch_c, W_c2, b_c2, out_value + (size_t)t0*B_DIM);
    }

    hipMemcpyAsync(out_hidden, h_carry, (size_t)B_DIM*H_DIM*sizeof(float),
                   hipMemcpyDeviceToDevice, stream);
}

// Round 3
// 10119.704 us; speedup vs baseline: 1.0896x; 1.0896x over previous
//
#include <hip/hip_runtime.h>
#include <stdint.h>

#define T_DIM 512
#define B_DIM 256
#define OBS_DIM 128
#define H_DIM 256
#define A_DIM 32
#define TB (T_DIM*B_DIM)   // 131072

typedef unsigned short u16;
typedef unsigned int   u32;

__device__ __forceinline__ float bf2f(u16 v){ return __uint_as_float(((u32)v)<<16); }
__device__ __forceinline__ u16 f2bf(float f){
    u32 x = __float_as_uint(f);
    u32 r = x + 0x7fffu + ((x>>16)&1u);   // round-to-nearest-even
    return (u16)(r>>16);
}
__device__ __forceinline__ float2 bfpair(u32 u){
    return make_float2(__uint_as_float(u<<16), __uint_as_float(u & 0xffff0000u));
}

// ---------------------------------------------------------------------------
// dones dtype probe (u8 bool vs i32 vs f32) via nonzero byte positions mod 4.
// bit0: nonzero @ pos%4==1 (only u8). bit1: nonzero @ pos%4>=2 (f32 1.0f).
// ---------------------------------------------------------------------------
__global__ void zero_flags_kernel(int* p){ if(threadIdx.x<4) p[threadIdx.x]=0; }

__global__ void detect_kernel(const unsigned char* __restrict__ d, int n, int* __restrict__ flags){
    int f=0;
    for(int p = blockIdx.x*blockDim.x+threadIdx.x; p<n; p += gridDim.x*blockDim.x){
        if(d[p]){ int m=p&3; if(m==1) f|=1; else if(m>=2) f|=2; }
    }
    if(f) atomicOr(flags, f);
}

// ---------------------------------------------------------------------------
// Recurrent weights -> transposed packed layout:
// Wt[(m*256 + j)*128 + kp] = pack(bf16(Wm[2kp][j]), bf16(Wm[2kp+1][j]))
// so thread (m,j) owns a contiguous 128-u32 column slice.
// ---------------------------------------------------------------------------
__global__ void cvt_wt_kernel(const float* __restrict__ Whr, const float* __restrict__ Whz,
                              const float* __restrict__ Whn, u32* __restrict__ dst){
    int i = blockIdx.x*blockDim.x + threadIdx.x;   // j fastest for coalesced reads
    if(i >= 3*128*256) return;
    int j  = i & 255;
    int kp = (i >> 8) & 127;
    int m  = i >> 15;
    const float* W = (m==0) ? Whr : (m==1) ? Whz : Whn;
    u16 lo = f2bf(W[(size_t)(2*kp  )*H_DIM + j]);
    u16 hi = f2bf(W[(size_t)(2*kp+1)*H_DIM + j]);
    dst[((size_t)m*256 + j)*128 + kp] = (u32)lo | ((u32)hi << 16);
}

// ---------------------------------------------------------------------------
// Generic f32-accumulate GEMM: C[M,N](bf16) = opt_relu(A[M,K] @ W[K,N] + bias)
// A f32 (ABF16=0) or bf16 (ABF16=1). 128x128 tile, BK=16, 256 thr, 8x8/thread.
// ---------------------------------------------------------------------------
template<int RELU, int ABF16>
__global__ __launch_bounds__(256)
void gemm_kernel(const void* __restrict__ A_, const float* __restrict__ W,
                 const float* __restrict__ bias, u16* __restrict__ C,
                 int M, int N, int K)
{
    __shared__ float As[16][128];   // As[k][m]
    __shared__ float Ws[16][128];   // Ws[k][n]
    const int tid = threadIdx.x;
    const int tr = tid>>4, tc = tid&15;
    const int lar = tid>>1, lac = (tid&1)*8;
    const int lwr = tid>>4, lwc = (tid&15)*8;
    const int rowBase = blockIdx.y*128;
    const int colBase = blockIdx.x*128;

    float acc[8][8];
    #pragma unroll
    for(int i=0;i<8;i++){
        #pragma unroll
        for(int j=0;j<8;j++) acc[i][j]=0.f;
    }

    for(int kb=0; kb<K; kb+=16){
        if(ABF16){
            const u16* Ab = (const u16*)A_;
            uint4 u = *(const uint4*)(Ab + (size_t)(rowBase+lar)*K + kb + lac);
            const u16* us = (const u16*)&u;
            #pragma unroll
            for(int i=0;i<8;i++) As[lac+i][lar] = bf2f(us[i]);
        } else {
            const float* Af = (const float*)A_;
            const float4* p = (const float4*)(Af + (size_t)(rowBase+lar)*K + kb + lac);
            float4 a0=p[0], a1=p[1];
            As[lac+0][lar]=a0.x; As[lac+1][lar]=a0.y; As[lac+2][lar]=a0.z; As[lac+3][lar]=a0.w;
            As[lac+4][lar]=a1.x; As[lac+5][lar]=a1.y; As[lac+6][lar]=a1.z; As[lac+7][lar]=a1.w;
        }
        {
            const float4* p = (const float4*)(W + (size_t)(kb+lwr)*N + colBase + lwc);
            float4 w0 = p[0], w1 = p[1];
            *(float4*)&Ws[lwr][lwc]   = w0;
            *(float4*)&Ws[lwr][lwc+4] = w1;
        }
        __syncthreads();
        #pragma unroll
        for(int kk=0;kk<16;kk++){
            float4 a0 = *(const float4*)&As[kk][tr*8];
            float4 a1 = *(const float4*)&As[kk][tr*8+4];
            float4 w0 = *(const float4*)&Ws[kk][tc*8];
            float4 w1 = *(const float4*)&Ws[kk][tc*8+4];
            float av[8]={a0.x,a0.y,a0.z,a0.w,a1.x,a1.y,a1.z,a1.w};
            float wv[8]={w0.x,w0.y,w0.z,w0.w,w1.x,w1.y,w1.z,w1.w};
            #pragma unroll
            for(int i=0;i<8;i++){
                #pragma unroll
                for(int j=0;j<8;j++) acc[i][j] = fmaf(av[i], wv[j], acc[i][j]);
            }
        }
        __syncthreads();
    }

    float bv[8];
    #pragma unroll
    for(int j=0;j<8;j++) bv[j] = bias[colBase + tc*8 + j];
    #pragma unroll
    for(int i=0;i<8;i++){
        u16 h[8];
        #pragma unroll
        for(int j=0;j<8;j++){
            float v = acc[i][j] + bv[j];
            if(RELU) v = fmaxf(v, 0.f);
            h[j] = f2bf(v);
        }
        *(uint4*)(C + (size_t)(rowBase + tr*8 + i)*N + colBase + tc*8) = *(uint4*)h;
    }
}

// ---------------------------------------------------------------------------
// GRU scan, one block per batch row (256 blocks x 768 threads).
// Thread (m = tid>>8, j = tid&255) owns output column j of matrix m with its
// 256-entry weight column register-resident as 128 packed-bf16 u32 (32 uint4).
// h is f32 in LDS; dot-phase float4 reads are wave-broadcast (conflict-free).
// Gate inputs (gi, next dones) are issued at dot-phase start so their HBM
// latency hides under the ~1.4us dot phase.
// ---------------------------------------------------------------------------
__global__ __launch_bounds__(768, 3)
void scan_kernel(const u16* __restrict__ gi, const void* __restrict__ dones,
                 const int* __restrict__ flags, const u32* __restrict__ Wt,
                 const float* __restrict__ bhn, float* __restrict__ h_carry,
                 u16* __restrict__ y, int t0, int Tc)
{
    __shared__ __align__(16) float hs[256];
    __shared__ float accb[768];
    const int tid = threadIdx.x;
    const int row = blockIdx.x;
    const int j   = tid & 255;
    const int m   = tid >> 8;
    const int fl  = flags[0];
    const int mode = (fl&1) ? 0 : ((fl&2) ? 2 : 1);  // 0=u8, 1=i32, 2=f32

    auto getdone = [&](int t)->bool{
        int idx = t*B_DIM + row;
        if(mode==0) return ((const unsigned char*)dones)[idx] != 0;
        if(mode==1) return ((const int*)dones)[idx] != 0;
        return ((const float*)dones)[idx] != 0.f;
    };

    // register-resident weight column slice (128 packed u32)
    uint4 wv[32];
    {
        const uint4* wp = (const uint4*)(Wt + ((size_t)m*256 + j)*128);
        #pragma unroll
        for(int q=0;q<32;q++) wv[q] = wp[q];
    }

    if(tid < 256){
        bool d0 = getdone(t0);
        hs[tid] = d0 ? 0.f : h_carry[(size_t)row*H_DIM + tid];
    }
    const float bh = (tid < 256) ? bhn[j] : 0.f;
    __syncthreads();

    for(int t=0; t<Tc; ++t){
        // issue gate-input loads now; they complete during the dot phase
        float ir=0.f, iz=0.f, inn=0.f; bool dn=false;
        if(tid < 256){
            size_t gbase = ((size_t)t*B_DIM + row)*768;
            ir  = bf2f(gi[gbase + j]);
            iz  = bf2f(gi[gbase + 256 + j]);
            inn = bf2f(gi[gbase + 512 + j]);
            dn  = (t < Tc-1) ? getdone(t0+t+1) : false;
        }

        // dot: acc = sum_k hs[k] * W_m[k][j]
        float acc0=0.f, acc1=0.f;
        const float4* hp = (const float4*)hs;
        #pragma unroll
        for(int q=0;q<32;q++){
            uint4 w = wv[q];
            float4 ha = hp[2*q];
            float4 hb = hp[2*q+1];
            float2 p0 = bfpair(w.x), p1 = bfpair(w.y);
            float2 p2 = bfpair(w.z), p3 = bfpair(w.w);
            acc0 = fmaf(ha.y, p0.y, fmaf(ha.x, p0.x, acc0));
            acc1 = fmaf(ha.w, p1.y, fmaf(ha.z, p1.x, acc1));
            acc0 = fmaf(hb.y, p2.y, fmaf(hb.x, p2.x, acc0));
            acc1 = fmaf(hb.w, p3.y, fmaf(hb.z, p3.x, acc1));
        }
        accb[tid] = acc0 + acc1;
        __syncthreads();

        if(tid < 256){
            float r = 1.f/(1.f + __expf(-(ir + accb[j])));
            float z = 1.f/(1.f + __expf(-(iz + accb[256+j])));
            float x = inn + r*(accb[512+j] + bh);
            float e2 = __expf(2.f*x);
            float n = 1.f - 2.f/(e2 + 1.f);        // tanh(x)
            float ho = hs[j];
            float hn = (1.f - z)*n + z*ho;
            hs[j] = dn ? 0.f : hn;                 // dn=false on chunk's last step
            y[((size_t)t*B_DIM + row)*H_DIM + j] = f2bf(hn);
        }
        __syncthreads();
    }

    if(tid < 256) h_carry[(size_t)row*H_DIM + tid] = hs[tid];
}

// ---------------------------------------------------------------------------
// Actor head stage 2: logits[rows,32] = ah[rows,256] @ W_a2 + b_a2 - (1-avail)*1e10
// ---------------------------------------------------------------------------
__global__ __launch_bounds__(256)
void actor2_kernel(const u16* __restrict__ ah, const float* __restrict__ W_a2,
                   const float* __restrict__ b_a2, const float* __restrict__ avail,
                   float* __restrict__ logits)
{
    __shared__ u16 ahs[64][264];
    const int tid = threadIdx.x;
    const int r0 = blockIdx.x*64;
    {
        int row = tid & 63;
        int c0 = (tid >> 6) * 64;
        const uint4* gp = (const uint4*)(ah + (size_t)(r0+row)*H_DIM + c0);
        #pragma unroll
        for(int q=0;q<8;q++){
            uint4 u = gp[q];
            u32* dst = (u32*)&ahs[row][c0 + q*8];
            dst[0]=u.x; dst[1]=u.y; dst[2]=u.z; dst[3]=u.w;
        }
    }
    __syncthreads();
    const int c  = tid & 31;
    const int rg = tid >> 5;   // 0..7
    float acc[8]={0.f,0.f,0.f,0.f,0.f,0.f,0.f,0.f};
    float bc = b_a2[c];
    for(int k=0;k<H_DIM;k+=4){
        float w0 = W_a2[(k+0)*A_DIM + c];
        float w1 = W_a2[(k+1)*A_DIM + c];
        float w2 = W_a2[(k+2)*A_DIM + c];
        float w3 = W_a2[(k+3)*A_DIM + c];
        #pragma unroll
        for(int rr=0;rr<8;rr++){
            uint2 av = *(const uint2*)&ahs[rg*8+rr][k];
            float2 p0 = bfpair(av.x), p1 = bfpair(av.y);
            acc[rr] = fmaf(p0.x,w0,fmaf(p0.y,w1,fmaf(p1.x,w2,fmaf(p1.y,w3,acc[rr]))));
        }
    }
    #pragma unroll
    for(int rr=0;rr<8;rr++){
        int grow = r0 + rg*8 + rr;
        float av = avail[(size_t)grow*A_DIM + c];
        logits[(size_t)grow*A_DIM + c] = acc[rr] + bc - (1.f-av)*1e10f;
    }
}

// ---------------------------------------------------------------------------
// Critic head stage 2: value[row] = ch[row,256] @ W_c2 + b_c2. Wave per row.
// ---------------------------------------------------------------------------
__global__ __launch_bounds__(256)
void critic2_kernel(const u16* __restrict__ ch, const float* __restrict__ W_c2,
                    const float* __restrict__ b_c2, float* __restrict__ value)
{
    const int lane = threadIdx.x & 63;
    const int wid  = threadIdx.x >> 6;
    const int row  = blockIdx.x*4 + wid;
    uint2 av = *(const uint2*)(ch + (size_t)row*H_DIM + lane*4);
    float2 p0 = bfpair(av.x), p1 = bfpair(av.y);
    float4 wv = *(const float4*)(W_c2 + lane*4);
    float acc = p0.x*wv.x + p0.y*wv.y + p1.x*wv.z + p1.y*wv.w;
    #pragma unroll
    for(int off=32; off>0; off>>=1) acc += __shfl_down(acc, off, 64);
    if(lane==0) value[row] = acc + b_c2[0];
}

// ---------------------------------------------------------------------------
extern "C" void kernel_launch(void* const* d_in, const int* in_sizes, int n_in,
                              void* d_out, int out_size, void* d_ws, size_t ws_size,
                              hipStream_t stream)
{
    const float* hidden = (const float*)d_in[0];
    const float* obs    = (const float*)d_in[1];
    const void*  dones  = d_in[2];
    const float* avail  = (const float*)d_in[3];
    const float* W_emb  = (const float*)d_in[4];
    const float* b_emb  = (const float*)d_in[5];
    const float* Wi     = (const float*)d_in[6];
    const float* bi     = (const float*)d_in[7];
    const float* Whr    = (const float*)d_in[8];
    const float* Whz    = (const float*)d_in[9];
    const float* Whn    = (const float*)d_in[10];
    const float* bhn    = (const float*)d_in[11];
    const float* W_a1   = (const float*)d_in[12];
    const float* b_a1   = (const float*)d_in[13];
    const float* W_a2   = (const float*)d_in[14];
    const float* b_a2   = (const float*)d_in[15];
    const float* W_c1   = (const float*)d_in[16];
    const float* b_c1   = (const float*)d_in[17];
    const float* W_c2   = (const float*)d_in[18];
    const float* b_c2   = (const float*)d_in[19];

    float* out_hidden = (float*)d_out;                       // 65536
    float* out_logits = out_hidden + (size_t)B_DIM*H_DIM;    // 4194304
    float* out_value  = out_logits + (size_t)TB*A_DIM;       // 131072

    // ---- workspace layout, chunk size adapted to ws_size (deterministic) ----
    const size_t fixed = 393216 /*wt*/ + 262144 /*h_carry*/ + 256 /*flags*/;
    int Tc = 4;
    for(int cand = 64; cand >= 4; cand >>= 1){
        size_t need = fixed + (size_t)cand*393216 /*gi*/ + (size_t)cand*4*131072 /*emb,y,ah,ch*/;
        if(need <= ws_size){ Tc = cand; break; }
    }
    const int NC = T_DIM / Tc;

    uint8_t* ws = (uint8_t*)d_ws;
    size_t off = 0;
    u32*  wt_b    = (u32*)(ws + off); off += 393216;
    float* h_carry= (float*)(ws + off); off += 262144;
    int*  flags   = (int*)(ws + off); off += 256;
    u16*  gi_c    = (u16*)(ws + off); off += (size_t)Tc*393216;
    u16*  emb_c   = (u16*)(ws + off); off += (size_t)Tc*131072;
    u16*  y_c     = (u16*)(ws + off); off += (size_t)Tc*131072;
    u16*  ah_c    = (u16*)(ws + off); off += (size_t)Tc*131072;
    u16*  ch_c    = (u16*)(ws + off); off += (size_t)Tc*131072;

    zero_flags_kernel<<<1, 64, 0, stream>>>(flags);
    detect_kernel<<<64, 256, 0, stream>>>((const unsigned char*)dones, TB, flags);
    cvt_wt_kernel<<<384, 256, 0, stream>>>(Whr, Whz, Whn, wt_b);
    hipMemcpyAsync(h_carry, hidden, (size_t)B_DIM*H_DIM*sizeof(float),
                   hipMemcpyDeviceToDevice, stream);

    const int Mc = Tc*B_DIM;          // rows per chunk
    const int gy = Mc/128;            // gemm grid.y

    for(int c = 0; c < NC; ++c){
        const int t0 = c*Tc;
        const float* obs_c = obs + (size_t)t0*B_DIM*OBS_DIM;
        // emb = relu(obs @ W_emb + b_emb)
        gemm_kernel<1,0><<<dim3(2,gy), 256, 0, stream>>>(obs_c, W_emb, b_emb, emb_c, Mc, 256, 128);
        // gi = emb @ Wi + bi
        gemm_kernel<0,1><<<dim3(6,gy), 256, 0, stream>>>(emb_c, Wi, bi, gi_c, Mc, 768, 256);
        // GRU scan chunk: 256 blocks (one per batch row) x 768 threads
        scan_kernel<<<256, 768, 0, stream>>>(gi_c, dones, flags, wt_b, bhn, h_carry, y_c, t0, Tc);
        // actor head
        gemm_kernel<1,1><<<dim3(2,gy), 256, 0, stream>>>(y_c, W_a1, b_a1, ah_c, Mc, 256, 256);
        actor2_kernel<<<Mc/64, 256, 0, stream>>>(ah_c, W_a2, b_a2,
                                                 avail + (size_t)t0*B_DIM*A_DIM,
                                                 out_logits + (size_t)t0*B_DIM*A_DIM);
        // critic head
        gemm_kernel<1,1><<<dim3(2,gy), 256, 0, stream>>>(y_c, W_c1, b_c1, ch_c, Mc, 256, 256);
        critic2_kernel<<<Mc/4, 256, 0, stream>>>(ch_c, W_c2, b_c2, out_value + (size_t)t0*B_DIM);
    }

    hipMemcpyAsync(out_hidden, h_carry, (size_t)B_DIM*H_DIM*sizeof(float),
                   hipMemcpyDeviceToDevice, stream);
}

// Round 4
// 2887.663 us; speedup vs baseline: 3.8184x; 3.5045x over previous
//
#include <hip/hip_runtime.h>
#include <stdint.h>

#define T_DIM 512
#define B_DIM 256
#define OBS_DIM 128
#define H_DIM 256
#define A_DIM 32
#define TB (T_DIM*B_DIM)   // 131072

typedef unsigned short u16;
typedef unsigned int   u32;
typedef _Float16 half2v __attribute__((ext_vector_type(2)));

__device__ __forceinline__ float bf2f(u16 v){ return __uint_as_float(((u32)v)<<16); }
__device__ __forceinline__ u16 f2bf(float f){
    u32 x = __float_as_uint(f);
    u32 r = x + 0x7fffu + ((x>>16)&1u);   // round-to-nearest-even
    return (u16)(r>>16);
}
__device__ __forceinline__ float2 bfpair(u32 u){
    return make_float2(__uint_as_float(u<<16), __uint_as_float(u & 0xffff0000u));
}

// packed-f16-pair dot: acc += a.lo*b.lo + a.hi*b.hi
__device__ __forceinline__ float dot2(u32 a, u32 b, float c){
#if __has_builtin(__builtin_amdgcn_fdot2)
    return __builtin_amdgcn_fdot2(__builtin_bit_cast(half2v,a),
                                  __builtin_bit_cast(half2v,b), c, false);
#else
    half2v ha = __builtin_bit_cast(half2v,a), hb = __builtin_bit_cast(half2v,b);
    return fmaf((float)ha[0],(float)hb[0], fmaf((float)ha[1],(float)hb[1], c));
#endif
}

// ---------------------------------------------------------------------------
// dones dtype probe (u8 bool vs i32 vs f32) via nonzero byte positions mod 4.
// ---------------------------------------------------------------------------
__global__ void zero_flags_kernel(int* p){ if(threadIdx.x<4) p[threadIdx.x]=0; }

__global__ void detect_kernel(const unsigned char* __restrict__ d, int n, int* __restrict__ flags){
    int f=0;
    for(int p = blockIdx.x*blockDim.x+threadIdx.x; p<n; p += gridDim.x*blockDim.x){
        if(d[p]){ int m=p&3; if(m==1) f|=1; else if(m>=2) f|=2; }
    }
    if(f) atomicOr(flags, f);
}

// ---------------------------------------------------------------------------
// Recurrent weights -> packed f16 pairs, layout dst[((m*32+q)*256 + j)*4 + e]:
// pair kp = 4q+e packs (k=2kp, 2kp+1) of column j of matrix m. A scan thread j
// then loads uint4 at ((m*32+q)*256+j) -- consecutive lanes 16B apart.
// ---------------------------------------------------------------------------
__global__ void cvt_wt_kernel(const float* __restrict__ Whr, const float* __restrict__ Whz,
                              const float* __restrict__ Whn, u32* __restrict__ dst){
    int i = blockIdx.x*blockDim.x + threadIdx.x;
    if(i >= 3*32*256*4) return;
    int e = i & 3;
    int j = (i >> 2) & 255;
    int q = (i >> 10) & 31;
    int m = i >> 15;
    const float* W = (m==0) ? Whr : (m==1) ? Whz : Whn;
    int kp = q*4 + e, k = 2*kp;
    _Float16 lo = (_Float16)W[(size_t)k    *H_DIM + j];
    _Float16 hi = (_Float16)W[(size_t)(k+1)*H_DIM + j];
    dst[i] = (u32)__builtin_bit_cast(u16,lo) | ((u32)__builtin_bit_cast(u16,hi) << 16);
}

// ---------------------------------------------------------------------------
// Generic f32-accumulate GEMM: C[M,N](bf16) = opt_relu(A[M,K] @ W[K,N] + bias)
// ---------------------------------------------------------------------------
template<int RELU, int ABF16>
__global__ __launch_bounds__(256)
void gemm_kernel(const void* __restrict__ A_, const float* __restrict__ W,
                 const float* __restrict__ bias, u16* __restrict__ C,
                 int M, int N, int K)
{
    __shared__ float As[16][128];   // As[k][m]
    __shared__ float Ws[16][128];   // Ws[k][n]
    const int tid = threadIdx.x;
    const int tr = tid>>4, tc = tid&15;
    const int lar = tid>>1, lac = (tid&1)*8;
    const int lwr = tid>>4, lwc = (tid&15)*8;
    const int rowBase = blockIdx.y*128;
    const int colBase = blockIdx.x*128;

    float acc[8][8];
    #pragma unroll
    for(int i=0;i<8;i++){
        #pragma unroll
        for(int j=0;j<8;j++) acc[i][j]=0.f;
    }

    for(int kb=0; kb<K; kb+=16){
        if(ABF16){
            const u16* Ab = (const u16*)A_;
            uint4 u = *(const uint4*)(Ab + (size_t)(rowBase+lar)*K + kb + lac);
            const u16* us = (const u16*)&u;
            #pragma unroll
            for(int i=0;i<8;i++) As[lac+i][lar] = bf2f(us[i]);
        } else {
            const float* Af = (const float*)A_;
            const float4* p = (const float4*)(Af + (size_t)(rowBase+lar)*K + kb + lac);
            float4 a0=p[0], a1=p[1];
            As[lac+0][lar]=a0.x; As[lac+1][lar]=a0.y; As[lac+2][lar]=a0.z; As[lac+3][lar]=a0.w;
            As[lac+4][lar]=a1.x; As[lac+5][lar]=a1.y; As[lac+6][lar]=a1.z; As[lac+7][lar]=a1.w;
        }
        {
            const float4* p = (const float4*)(W + (size_t)(kb+lwr)*N + colBase + lwc);
            float4 w0 = p[0], w1 = p[1];
            *(float4*)&Ws[lwr][lwc]   = w0;
            *(float4*)&Ws[lwr][lwc+4] = w1;
        }
        __syncthreads();
        #pragma unroll
        for(int kk=0;kk<16;kk++){
            float4 a0 = *(const float4*)&As[kk][tr*8];
            float4 a1 = *(const float4*)&As[kk][tr*8+4];
            float4 w0 = *(const float4*)&Ws[kk][tc*8];
            float4 w1 = *(const float4*)&Ws[kk][tc*8+4];
            float av[8]={a0.x,a0.y,a0.z,a0.w,a1.x,a1.y,a1.z,a1.w};
            float wv[8]={w0.x,w0.y,w0.z,w0.w,w1.x,w1.y,w1.z,w1.w};
            #pragma unroll
            for(int i=0;i<8;i++){
                #pragma unroll
                for(int j=0;j<8;j++) acc[i][j] = fmaf(av[i], wv[j], acc[i][j]);
            }
        }
        __syncthreads();
    }

    float bv[8];
    #pragma unroll
    for(int j=0;j<8;j++) bv[j] = bias[colBase + tc*8 + j];
    #pragma unroll
    for(int i=0;i<8;i++){
        u16 h[8];
        #pragma unroll
        for(int j=0;j<8;j++){
            float v = acc[i][j] + bv[j];
            if(RELU) v = fmaxf(v, 0.f);
            h[j] = f2bf(v);
        }
        *(uint4*)(C + (size_t)(rowBase + tr*8 + i)*N + colBase + tc*8) = *(uint4*)h;
    }
}

// ---------------------------------------------------------------------------
// GRU scan: 256 blocks (one batch row) x 256 threads (one output column j).
// Thread j holds columns j of Whr/Whz/Whn register-resident as 3x32 uint4 of
// packed f16 pairs (384 VGPRs; __launch_bounds__(256,1) allows up to 512).
// h double-buffered in LDS as packed f16 (512B), read via broadcast uint4.
// One barrier per step. r/z/n partials stay in registers (no LDS round-trip).
// ---------------------------------------------------------------------------
__global__ __launch_bounds__(256, 1)
void scan_kernel(const u16* __restrict__ gi, const void* __restrict__ dones,
                 const int* __restrict__ flags, const uint4* __restrict__ Wt4,
                 const float* __restrict__ bhn, float* __restrict__ h_carry,
                 u16* __restrict__ y, int t0, int Tc)
{
    __shared__ __align__(16) u32 hbuf[2][128];   // 256 packed f16 each
    const int j   = threadIdx.x;
    const int row = blockIdx.x;
    const int fl  = flags[0];
    const int mode = (fl&1) ? 0 : ((fl&2) ? 2 : 1);  // 0=u8, 1=i32, 2=f32

    auto getdone = [&](int t)->bool{
        int idx = t*B_DIM + row;
        if(mode==0) return ((const unsigned char*)dones)[idx] != 0;
        if(mode==1) return ((const int*)dones)[idx] != 0;
        return ((const float*)dones)[idx] != 0.f;
    };

    // one-time register-resident weight load: 96 coalesced dwordx4 per thread
    uint4 w[3][32];
    #pragma unroll
    for(int m=0;m<3;m++){
        #pragma unroll
        for(int q=0;q<32;q++) w[m][q] = Wt4[(size_t)(m*32+q)*256 + j];
    }

    const float bh = bhn[j];
    bool d0 = getdone(t0);
    float ho = d0 ? 0.f : h_carry[(size_t)row*H_DIM + j];
    ((_Float16*)hbuf[0])[j] = (_Float16)ho;
    __syncthreads();

    int cur = 0;
    for(int t=0; t<Tc; ++t){
        // gate-input loads issued up front; latency hides under the dot phase
        size_t gbase = ((size_t)t*B_DIM + row)*768;
        float ir  = bf2f(gi[gbase + j]);
        float iz  = bf2f(gi[gbase + 256 + j]);
        float inn = bf2f(gi[gbase + 512 + j]);
        bool  dn  = (t < Tc-1) ? getdone(t0+t+1) : false;

        float ar0=0.f, ar1=0.f, az0=0.f, az1=0.f, an0=0.f, an1=0.f;
        const uint4* hb = (const uint4*)hbuf[cur];
        #pragma unroll
        for(int q=0;q<32;q++){
            uint4 hv = hb[q];
            ar0 = dot2(w[0][q].x, hv.x, ar0); ar1 = dot2(w[0][q].y, hv.y, ar1);
            ar0 = dot2(w[0][q].z, hv.z, ar0); ar1 = dot2(w[0][q].w, hv.w, ar1);
            az0 = dot2(w[1][q].x, hv.x, az0); az1 = dot2(w[1][q].y, hv.y, az1);
            az0 = dot2(w[1][q].z, hv.z, az0); az1 = dot2(w[1][q].w, hv.w, az1);
            an0 = dot2(w[2][q].x, hv.x, an0); an1 = dot2(w[2][q].y, hv.y, an1);
            an0 = dot2(w[2][q].z, hv.z, an0); an1 = dot2(w[2][q].w, hv.w, an1);
        }
        float r = 1.f/(1.f + __expf(-(ir + ar0 + ar1)));
        float z = 1.f/(1.f + __expf(-(iz + az0 + az1)));
        float x = inn + r*(an0 + an1 + bh);
        float e2 = __expf(2.f*x);
        float n = 1.f - 2.f/(e2 + 1.f);          // tanh(x)
        float hn = (1.f - z)*n + z*ho;
        y[((size_t)t*B_DIM + row)*H_DIM + j] = f2bf(hn);
        ho = dn ? 0.f : hn;                      // reset pre-applied for next step
        ((_Float16*)hbuf[cur^1])[j] = (_Float16)ho;
        __syncthreads();
        cur ^= 1;
    }

    h_carry[(size_t)row*H_DIM + j] = ho;         // raw carry (no next-step reset)
}

// ---------------------------------------------------------------------------
// Actor head stage 2: logits[rows,32] = ah[rows,256] @ W_a2 + b_a2 - (1-avail)*1e10
// ---------------------------------------------------------------------------
__global__ __launch_bounds__(256)
void actor2_kernel(const u16* __restrict__ ah, const float* __restrict__ W_a2,
                   const float* __restrict__ b_a2, const float* __restrict__ avail,
                   float* __restrict__ logits)
{
    __shared__ u16 ahs[64][264];
    const int tid = threadIdx.x;
    const int r0 = blockIdx.x*64;
    {
        int row = tid & 63;
        int c0 = (tid >> 6) * 64;
        const uint4* gp = (const uint4*)(ah + (size_t)(r0+row)*H_DIM + c0);
        #pragma unroll
        for(int q=0;q<8;q++){
            uint4 u = gp[q];
            u32* dst = (u32*)&ahs[row][c0 + q*8];
            dst[0]=u.x; dst[1]=u.y; dst[2]=u.z; dst[3]=u.w;
        }
    }
    __syncthreads();
    const int c  = tid & 31;
    const int rg = tid >> 5;   // 0..7
    float acc[8]={0.f,0.f,0.f,0.f,0.f,0.f,0.f,0.f};
    float bc = b_a2[c];
    for(int k=0;k<H_DIM;k+=4){
        float w0 = W_a2[(k+0)*A_DIM + c];
        float w1 = W_a2[(k+1)*A_DIM + c];
        float w2 = W_a2[(k+2)*A_DIM + c];
        float w3 = W_a2[(k+3)*A_DIM + c];
        #pragma unroll
        for(int rr=0;rr<8;rr++){
            uint2 av = *(const uint2*)&ahs[rg*8+rr][k];
            float2 p0 = bfpair(av.x), p1 = bfpair(av.y);
            acc[rr] = fmaf(p0.x,w0,fmaf(p0.y,w1,fmaf(p1.x,w2,fmaf(p1.y,w3,acc[rr]))));
        }
    }
    #pragma unroll
    for(int rr=0;rr<8;rr++){
        int grow = r0 + rg*8 + rr;
        float av = avail[(size_t)grow*A_DIM + c];
        logits[(size_t)grow*A_DIM + c] = acc[rr] + bc - (1.f-av)*1e10f;
    }
}

// ---------------------------------------------------------------------------
// Critic head stage 2: value[row] = ch[row,256] @ W_c2 + b_c2. Wave per row.
// ---------------------------------------------------------------------------
__global__ __launch_bounds__(256)
void critic2_kernel(const u16* __restrict__ ch, const float* __restrict__ W_c2,
                    const float* __restrict__ b_c2, float* __restrict__ value)
{
    const int lane = threadIdx.x & 63;
    const int wid  = threadIdx.x >> 6;
    const int row  = blockIdx.x*4 + wid;
    uint2 av = *(const uint2*)(ch + (size_t)row*H_DIM + lane*4);
    float2 p0 = bfpair(av.x), p1 = bfpair(av.y);
    float4 wv = *(const float4*)(W_c2 + lane*4);
    float acc = p0.x*wv.x + p0.y*wv.y + p1.x*wv.z + p1.y*wv.w;
    #pragma unroll
    for(int off=32; off>0; off>>=1) acc += __shfl_down(acc, off, 64);
    if(lane==0) value[row] = acc + b_c2[0];
}

// ---------------------------------------------------------------------------
extern "C" void kernel_launch(void* const* d_in, const int* in_sizes, int n_in,
                              void* d_out, int out_size, void* d_ws, size_t ws_size,
                              hipStream_t stream)
{
    const float* hidden = (const float*)d_in[0];
    const float* obs    = (const float*)d_in[1];
    const void*  dones  = d_in[2];
    const float* avail  = (const float*)d_in[3];
    const float* W_emb  = (const float*)d_in[4];
    const float* b_emb  = (const float*)d_in[5];
    const float* Wi     = (const float*)d_in[6];
    const float* bi     = (const float*)d_in[7];
    const float* Whr    = (const float*)d_in[8];
    const float* Whz    = (const float*)d_in[9];
    const float* Whn    = (const float*)d_in[10];
    const float* bhn    = (const float*)d_in[11];
    const float* W_a1   = (const float*)d_in[12];
    const float* b_a1   = (const float*)d_in[13];
    const float* W_a2   = (const float*)d_in[14];
    const float* b_a2   = (const float*)d_in[15];
    const float* W_c1   = (const float*)d_in[16];
    const float* b_c1   = (const float*)d_in[17];
    const float* W_c2   = (const float*)d_in[18];
    const float* b_c2   = (const float*)d_in[19];

    float* out_hidden = (float*)d_out;                       // 65536
    float* out_logits = out_hidden + (size_t)B_DIM*H_DIM;    // 4194304
    float* out_value  = out_logits + (size_t)TB*A_DIM;       // 131072

    // ---- workspace layout, chunk size adapted to ws_size (deterministic) ----
    const size_t fixed = 393216 /*wt*/ + 262144 /*h_carry*/ + 256 /*flags*/;
    int Tc = 4;
    for(int cand = 64; cand >= 4; cand >>= 1){
        size_t need = fixed + (size_t)cand*393216 /*gi*/ + (size_t)cand*4*131072 /*emb,y,ah,ch*/;
        if(need <= ws_size){ Tc = cand; break; }
    }
    const int NC = T_DIM / Tc;

    uint8_t* ws = (uint8_t*)d_ws;
    size_t off = 0;
    u32*  wt_b    = (u32*)(ws + off); off += 393216;
    float* h_carry= (float*)(ws + off); off += 262144;
    int*  flags   = (int*)(ws + off); off += 256;
    u16*  gi_c    = (u16*)(ws + off); off += (size_t)Tc*393216;
    u16*  emb_c   = (u16*)(ws + off); off += (size_t)Tc*131072;
    u16*  y_c     = (u16*)(ws + off); off += (size_t)Tc*131072;
    u16*  ah_c    = (u16*)(ws + off); off += (size_t)Tc*131072;
    u16*  ch_c    = (u16*)(ws + off); off += (size_t)Tc*131072;

    zero_flags_kernel<<<1, 64, 0, stream>>>(flags);
    detect_kernel<<<64, 256, 0, stream>>>((const unsigned char*)dones, TB, flags);
    cvt_wt_kernel<<<384, 256, 0, stream>>>(Whr, Whz, Whn, wt_b);
    hipMemcpyAsync(h_carry, hidden, (size_t)B_DIM*H_DIM*sizeof(float),
                   hipMemcpyDeviceToDevice, stream);

    const int Mc = Tc*B_DIM;          // rows per chunk
    const int gy = Mc/128;            // gemm grid.y

    for(int c = 0; c < NC; ++c){
        const int t0 = c*Tc;
        const float* obs_c = obs + (size_t)t0*B_DIM*OBS_DIM;
        // emb = relu(obs @ W_emb + b_emb)
        gemm_kernel<1,0><<<dim3(2,gy), 256, 0, stream>>>(obs_c, W_emb, b_emb, emb_c, Mc, 256, 128);
        // gi = emb @ Wi + bi
        gemm_kernel<0,1><<<dim3(6,gy), 256, 0, stream>>>(emb_c, Wi, bi, gi_c, Mc, 768, 256);
        // GRU scan chunk: 256 blocks (one per batch row) x 256 threads
        scan_kernel<<<256, 256, 0, stream>>>(gi_c, dones, flags, (const uint4*)wt_b,
                                             bhn, h_carry, y_c, t0, Tc);
        // actor head
        gemm_kernel<1,1><<<dim3(2,gy), 256, 0, stream>>>(y_c, W_a1, b_a1, ah_c, Mc, 256, 256);
        actor2_kernel<<<Mc/64, 256, 0, stream>>>(ah_c, W_a2, b_a2,
                                                 avail + (size_t)t0*B_DIM*A_DIM,
                                                 out_logits + (size_t)t0*B_DIM*A_DIM);
        // critic head
        gemm_kernel<1,1><<<dim3(2,gy), 256, 0, stream>>>(y_c, W_c1, b_c1, ch_c, Mc, 256, 256);
        critic2_kernel<<<Mc/4, 256, 0, stream>>>(ch_c, W_c2, b_c2, out_value + (size_t)t0*B_DIM);
    }

    hipMemcpyAsync(out_hidden, h_carry, (size_t)B_DIM*H_DIM*sizeof(float),
                   hipMemcpyDeviceToDevice, stream);
}